// Round 10
// baseline (114.455 us; speedup 1.0000x reference)
//
#include <hip/hip_runtime.h>
#include <hip/hip_bf16.h>

// Problem constants (JointAnfisNet)
#define BATCH      16384
#define N_IN       6
#define N_MF       5
#define N_FUZZ     30      // N_IN * N_MF
#define N_RULES    2048

// R10: f16x8 row packing (ds_read_b128 gathers). Evidence: R3's unpacked
// kernel matched the LDS-issue model exactly (6 cyc/b32 indexed), while all
// b64 variants imply ~19.5 cyc per indexed b64 -> large per-instruction
// fixed cost. Fewer, wider gathers amortize it: 6 b128/rule serve 8 rows.
//   grid = 32 row-groups x 8 rule-splits = 256 blocks (1/CU, 16 waves).
//   lane covers rows {l+64k, k=0..7}; wave handles 16 rules.
//   Cross-wave reduction: LDS float atomics acc[3][512] (wave-partial arrays
//   would need 96 KB; R7's atomic regression is attributed to its VGPR=20
//   strangulation, not the atomics — here VGPR cap is 128).
#define ROWS_PB    512
#define SPLITS     8
#define RULES_PB   (N_RULES / SPLITS)     // 256
#define THREADS    1024
#define WAVES      16
#define RULES_PW   (RULES_PB / WAVES)     // 16
#define ROWGROUPS  (BATCH / ROWS_PB)      // 32

// d_ws layout: partials f32[SPLITS*3*BATCH] = 1.5 MB
#define WS_PART_OFF  0

typedef _Float16 f16x2 __attribute__((ext_vector_type(2)));

// ---------------------------------------------------------------------------
// Deterministic dtype probe (branchless, 15 independent loads, one wait).
// mf_scales is genuinely in [0.5,1.5]; read as 30 bf16 halves, all-in-
// [0.4,1.6] => bf16 data (P(false positive for f32) ~ 1e-32). R3..R9 passed.
// ---------------------------------------------------------------------------
__device__ inline bool probe_is_bf16(const void* mfs) {
    const unsigned int* w = (const unsigned int*)mfs;
    bool ok = true;
#pragma unroll
    for (int k = 0; k < 15; ++k) {
        const unsigned int v = w[k];
        const float lo = __uint_as_float(v << 16);
        const float hi = __uint_as_float(v & 0xffff0000u);
        ok = ok && (lo >= 0.4f) && (lo <= 1.6f) && (hi >= 0.4f) && (hi <= 1.6f);
    }
    return ok;
}

// Elementwise min of two f16x2 words (lowers to v_pk_min_f16).
__device__ inline unsigned int minw(unsigned int a, unsigned int b) {
    const f16x2 r = __builtin_elementwise_min(__builtin_bit_cast(f16x2, a),
                                              __builtin_bit_cast(f16x2, b));
    return __builtin_bit_cast(unsigned int, r);
}

__global__ __launch_bounds__(THREADS, 4)   // VGPR cap 128 (R8: cap 64 strangled ILP)
void anfis_main(const void* __restrict__ x_,
                const void* __restrict__ mfc_,
                const void* __restrict__ mfs_,
                const void* __restrict__ oc_,
                const int*  __restrict__ input_rules,
                const int*  __restrict__ output_rules,
                float* __restrict__ partials) {
    __shared__ float        xs[N_IN][ROWS_PB];    // 12 KB transposed
    __shared__ float2       cinv[N_FUZZ];         // (center, 1/scale)
    __shared__ uint4        fuzz8[N_FUZZ][64];    // 30 KB, 8 rows/lane f16x8
    __shared__ unsigned int packed_lds[RULES_PB]; // 1 KB (this block's split)
    __shared__ float2       ow_lds[RULES_PB];     // 2 KB
    __shared__ float        acc[3][ROWS_PB];      // 6 KB: l1/d0/d1 per row

    const int t     = threadIdx.x;
    const int g     = blockIdx.x >> 3;            // row group 0..31
    const int split = blockIdx.x & 7;             // rule split 0..7
    const int row0  = g * ROWS_PB;

    const bool is_bf16 = probe_is_bf16(mfs_);

    // ---- region 1: stage x (transposed) + MF params; stage rules; zero acc ----
    if (is_bf16) {
        const unsigned short* xp = (const unsigned short*)x_ + row0 * N_IN;
        for (int i = t; i < ROWS_PB * N_IN; i += THREADS)
            xs[i % N_IN][i / N_IN] = __uint_as_float((unsigned int)xp[i] << 16);
    } else {
        const float* xp = (const float*)x_ + row0 * N_IN;
        for (int i = t; i < ROWS_PB * N_IN; i += THREADS)
            xs[i % N_IN][i / N_IN] = xp[i];
    }
    if (t < N_FUZZ) {
        float c, s;
        if (is_bf16) {
            c = __uint_as_float((unsigned int)((const unsigned short*)mfc_)[t] << 16);
            s = __uint_as_float((unsigned int)((const unsigned short*)mfs_)[t] << 16);
        } else {
            c = ((const float*)mfc_)[t];
            s = ((const float*)mfs_)[t];
        }
        cinv[t] = make_float2(c, 1.0f / s);
    }
    if (t < RULES_PB) {
        const int r = split * RULES_PB + t;
        const int* rp = input_rules + r * N_IN;
        unsigned int p = 0;
#pragma unroll
        for (int i = 0; i < N_IN; ++i) p |= ((unsigned int)rp[i] & 31u) << (5 * i);
        packed_lds[t] = p;
        const int o0i = output_rules[2 * r + 0];
        const int o1i = output_rules[2 * r + 1];
        float o0, o1;
        if (is_bf16) {
            const unsigned short* oc = (const unsigned short*)oc_;
            o0 = __uint_as_float((unsigned int)oc[o0i] << 16);
            o1 = __uint_as_float((unsigned int)oc[o1i] << 16);
        } else {
            const float* oc = (const float*)oc_;
            o0 = oc[o0i]; o1 = oc[o1i];
        }
        ow_lds[t] = make_float2(o0, o1);
    }
    for (int i = t; i < 3 * ROWS_PB; i += THREADS) acc[0][i] = 0.0f;
    __syncthreads();

    // ---- region 2: fuzzify. 30 x 64 uint4, each = 8 rows' exp(-z^2) f16 ----
    for (int e = t; e < N_FUZZ * 64; e += THREADS) {
        const int v    = e >> 6;    // MF value index 0..29
        const int lane = e & 63;
        const int i    = v / N_MF;  // input index
        const float2 ci = cinv[v];
        float f[8];
#pragma unroll
        for (int k = 0; k < 8; ++k) {
            const float z = (xs[i][lane + 64 * k] - ci.x) * ci.y;
            f[k] = __expf(-z * z);
        }
        uint4 u;
        {
            f16x2 a = { (_Float16)f[0], (_Float16)f[1] };
            f16x2 b = { (_Float16)f[2], (_Float16)f[3] };
            f16x2 c = { (_Float16)f[4], (_Float16)f[5] };
            f16x2 d = { (_Float16)f[6], (_Float16)f[7] };
            u.x = __builtin_bit_cast(unsigned int, a);
            u.y = __builtin_bit_cast(unsigned int, b);
            u.z = __builtin_bit_cast(unsigned int, c);
            u.w = __builtin_bit_cast(unsigned int, d);
        }
        fuzz8[v][lane] = u;
    }
    __syncthreads();

    // ---- region 3: rule loop. 6 indexed ds_read_b128 per rule serve 8 rows ----
    const int lane = t & 63;
    const int wave = __builtin_amdgcn_readfirstlane(t >> 6);
    const uint4* fz = &fuzz8[0][0];

    float l1[8], d0[8], d1[8];
#pragma unroll
    for (int k = 0; k < 8; ++k) { l1[k] = 0.f; d0[k] = 0.f; d1[k] = 0.f; }

    const int rbase = wave * RULES_PW;
#pragma unroll 4
    for (int j = 0; j < RULES_PW; ++j) {
        const int r2 = rbase + j;
        const unsigned int p = packed_lds[r2];   // LDS broadcast
        const float2 o = ow_lds[r2];             // LDS broadcast
        uint4 gq[6];
#pragma unroll
        for (int q = 0; q < 6; ++q)
            gq[q] = fz[((p >> (5 * q)) & 31u) * 64 + lane];

        // min tree over the 6 gathers, per 32-bit component (depth 3)
        unsigned int m0, m1, m2, m3;
        {
            const unsigned int a0 = minw(gq[0].x, gq[1].x);
            const unsigned int b0 = minw(gq[2].x, gq[3].x);
            const unsigned int c0 = minw(gq[4].x, gq[5].x);
            m0 = minw(minw(a0, b0), c0);
            const unsigned int a1 = minw(gq[0].y, gq[1].y);
            const unsigned int b1 = minw(gq[2].y, gq[3].y);
            const unsigned int c1 = minw(gq[4].y, gq[5].y);
            m1 = minw(minw(a1, b1), c1);
            const unsigned int a2 = minw(gq[0].z, gq[1].z);
            const unsigned int b2 = minw(gq[2].z, gq[3].z);
            const unsigned int c2 = minw(gq[4].z, gq[5].z);
            m2 = minw(minw(a2, b2), c2);
            const unsigned int a3 = minw(gq[0].w, gq[1].w);
            const unsigned int b3 = minw(gq[2].w, gq[3].w);
            const unsigned int c3 = minw(gq[4].w, gq[5].w);
            m3 = minw(minw(a3, b3), c3);
        }
        const f16x2 h0 = __builtin_bit_cast(f16x2, m0);
        const f16x2 h1 = __builtin_bit_cast(f16x2, m1);
        const f16x2 h2 = __builtin_bit_cast(f16x2, m2);
        const f16x2 h3 = __builtin_bit_cast(f16x2, m3);
        const float w0 = (float)h0.x, w1 = (float)h0.y;
        const float w2 = (float)h1.x, w3 = (float)h1.y;
        const float w4 = (float)h2.x, w5 = (float)h2.y;
        const float w6 = (float)h3.x, w7 = (float)h3.y;
        l1[0] += w0; d0[0] += w0 * o.x; d1[0] += w0 * o.y;
        l1[1] += w1; d0[1] += w1 * o.x; d1[1] += w1 * o.y;
        l1[2] += w2; d0[2] += w2 * o.x; d1[2] += w2 * o.y;
        l1[3] += w3; d0[3] += w3 * o.x; d1[3] += w3 * o.y;
        l1[4] += w4; d0[4] += w4 * o.x; d1[4] += w4 * o.y;
        l1[5] += w5; d0[5] += w5 * o.x; d1[5] += w5 * o.y;
        l1[6] += w6; d0[6] += w6 * o.x; d1[6] += w6 * o.y;
        l1[7] += w7; d0[7] += w7 * o.x; d1[7] += w7 * o.y;
    }

    // ---- cross-wave reduction: ds_add_f32; lanes hit distinct rows ----
#pragma unroll
    for (int k = 0; k < 8; ++k) {
        const int row = lane + 64 * k;
        atomicAdd(&acc[0][row], l1[k]);
        atomicAdd(&acc[1][row], d0[k]);
        atomicAdd(&acc[2][row], d1[k]);
    }
    __syncthreads();

    // ---- write this split's partials ----
    if (t < ROWS_PB) {
        const int row = row0 + t;
        partials[(split * 3 + 0) * BATCH + row] = acc[0][t];
        partials[(split * 3 + 1) * BATCH + row] = acc[1][t];
        partials[(split * 3 + 2) * BATCH + row] = acc[2][t];
    }
}

// ---------------------------------------------------------------------------
// Finalize: sum the 8 rule-split partials per row, normalize, tanh, store.
// ---------------------------------------------------------------------------
__global__ void anfis_finalize(const float* __restrict__ partials,
                               const void* __restrict__ mfs_,
                               void* __restrict__ out_) {
    const bool is_bf16 = probe_is_bf16(mfs_);
    const int row = blockIdx.x * blockDim.x + threadIdx.x;
    if (row >= BATCH) return;
    float l1 = 0.f, d0 = 0.f, d1 = 0.f;
#pragma unroll
    for (int s = 0; s < SPLITS; ++s) {
        l1 += partials[(s * 3 + 0) * BATCH + row];
        d0 += partials[(s * 3 + 1) * BATCH + row];
        d1 += partials[(s * 3 + 2) * BATCH + row];
    }
    const float inv = 1.0f / fmaxf(l1, 1e-12f);
    const float y0 = tanhf(d0 * inv) * 4.00f + 0.00f;
    const float y1 = tanhf(d1 * inv) * 0.75f + 0.75f;
    if (is_bf16) {
        __hip_bfloat162 o;
        o.x = __float2bfloat16(y0);
        o.y = __float2bfloat16(y1);
        ((__hip_bfloat162*)out_)[row] = o;
    } else {
        ((float2*)out_)[row] = make_float2(y0, y1);
    }
}

extern "C" void kernel_launch(void* const* d_in, const int* in_sizes, int n_in,
                              void* d_out, int out_size, void* d_ws, size_t ws_size,
                              hipStream_t stream) {
    (void)in_sizes; (void)n_in; (void)out_size; (void)ws_size;
    float* parts = (float*)((char*)d_ws + WS_PART_OFF);

    anfis_main<<<ROWGROUPS * SPLITS, THREADS, 0, stream>>>(
        d_in[0], d_in[1], d_in[2], d_in[3],
        (const int*)d_in[4], (const int*)d_in[5], parts);

    anfis_finalize<<<BATCH / 256, 256, 0, stream>>>(parts, d_in[2], d_out);
}